// Round 6
// baseline (581.538 us; speedup 1.0000x reference)
//
#include <hip/hip_runtime.h>
#include <math.h>

#define BD 8
#define CD 256
#define ND 4096
#define DA 64

typedef __attribute__((ext_vector_type(8))) short short8v;
typedef __attribute__((ext_vector_type(4))) float float4v;

static __device__ __forceinline__ float4v mfma16(short8v a, short8v b, float4v c) {
  return __builtin_amdgcn_mfma_f32_16x16x32_bf16(a, b, c, 0, 0, 0);
}
static __device__ __forceinline__ unsigned short f2bf(float f) {
  union { float f; unsigned int u; } v; v.f = f;
  return (unsigned short)((v.u + 0x7fffu + ((v.u >> 16) & 1u)) >> 16);
}
static __device__ __forceinline__ float bf2f(unsigned short h) {
  union { unsigned int u; float f; } v; v.u = (unsigned int)h << 16;
  return v.f;
}
// XOR-swizzled LDS offset (ushort units) for rows of 64 bf16 (8 x 16B chunks).
static __device__ __forceinline__ int sw(int row, int c8) {
  return row * 64 + (((c8) ^ (row & 7)) << 3);
}
typedef const __attribute__((address_space(1))) unsigned int g_u32;
typedef __attribute__((address_space(3))) unsigned int l_u32;
static __device__ __forceinline__ void gld16(const void* g, void* l) {
  __builtin_amdgcn_global_load_lds((g_u32*)g, (l_u32*)l, 16, 0, 0);
}

// ---------------------------------------------------------------------------
// k_prep: x [b][c][n] fp32 -> xTh/xTl [b][n][256] split bf16 (transposed).
// ---------------------------------------------------------------------------
__global__ __launch_bounds__(256) void k_prep(const float* __restrict__ x,
                                              unsigned short* __restrict__ xTh,
                                              unsigned short* __restrict__ xTl) {
  const int n0 = blockIdx.x * 64, c0 = blockIdx.y * 64, b = blockIdx.z;
  __shared__ float Xs[64][68];
  const int tid = threadIdx.x;
  const int r0 = tid >> 4, col4 = (tid & 15) * 4;
#pragma unroll
  for (int j = 0; j < 4; ++j) {
    int r = r0 + j * 16;
    *(float4*)&Xs[r][col4] =
        *(const float4*)&x[((size_t)(b * CD + c0 + r)) * ND + n0 + col4];
  }
  __syncthreads();
  const int n = tid >> 2, cg = (tid & 3) * 16;
  unsigned short h[16], l[16];
#pragma unroll
  for (int j = 0; j < 16; ++j) {
    float v = Xs[cg + j][n];
    h[j] = f2bf(v);
    l[j] = f2bf(v - bf2f(h[j]));
  }
  size_t o = ((size_t)b * ND + n0 + n) * CD + c0 + cg;
#pragma unroll
  for (int j = 0; j < 4; ++j) {
    *(ushort4*)&xTh[o + j * 4] = *(ushort4*)&h[j * 4];
    *(ushort4*)&xTl[o + j * 4] = *(ushort4*)&l[j * 4];
  }
}

// ---------------------------------------------------------------------------
// k_prepW: split weights fp32 -> bf16 hi/lo. Wch/Wcl = [Wq;Wk;Wv] rows 0..383.
// grid 160 x 256.
// ---------------------------------------------------------------------------
__global__ void k_prepW(const float* __restrict__ Wq, const float* __restrict__ Wk,
                        const float* __restrict__ Wv, const float* __restrict__ Wp,
                        unsigned short* Wch, unsigned short* Wcl,
                        unsigned short* Wph, unsigned short* Wpl) {
  int i = blockIdx.x * 256 + threadIdx.x;  // 640 rows x 64 float4
  int row = i >> 6, c4 = (i & 63) * 4;
  const float* src; unsigned short *dh, *dl; int r, drow;
  if (row < 64)       { src = Wq; r = row;       dh = Wch; dl = Wcl; drow = row; }
  else if (row < 128) { src = Wk; r = row - 64;  dh = Wch; dl = Wcl; drow = row; }
  else if (row < 384) { src = Wv; r = row - 128; dh = Wch; dl = Wcl; drow = row; }
  else                { src = Wp; r = row - 384; dh = Wph; dl = Wpl; drow = row - 384; }
  float4 f = *(const float4*)&src[(size_t)r * 256 + c4];
  ushort4 hh, ll;
  hh.x = f2bf(f.x); hh.y = f2bf(f.y); hh.z = f2bf(f.z); hh.w = f2bf(f.w);
  ll.x = f2bf(f.x - bf2f(hh.x)); ll.y = f2bf(f.y - bf2f(hh.y));
  ll.z = f2bf(f.z - bf2f(hh.z)); ll.w = f2bf(f.w - bf2f(hh.w));
  *(ushort4*)&dh[(size_t)drow * 256 + c4] = hh;
  *(ushort4*)&dl[(size_t)drow * 256 + c4] = ll;
}

// ---------------------------------------------------------------------------
// k_proj: MERGED q/k/v projection. Reads xT once per block (LDS k-slices),
// computes all 384 output rows (q:0-63, k:64-127, v:128-383), 3-product MFMA.
// grid (ND/128, B), 512 thr = 8 waves, wave owns 16 n-rows x all 384 d.
// Outputs: qh [b][n][64] (hi only - ql unused under 2-product e),
//          kh/kl [b][n][64] split, vT [b][c][m] bf16.
// ---------------------------------------------------------------------------
__global__ __launch_bounds__(512) void k_proj(
    const unsigned short* __restrict__ xTh, const unsigned short* __restrict__ xTl,
    const unsigned short* __restrict__ Wch, const unsigned short* __restrict__ Wcl,
    unsigned short* __restrict__ qh, unsigned short* __restrict__ kh,
    unsigned short* __restrict__ kl, unsigned short* __restrict__ vT) {
  const int n0 = blockIdx.x * 128, b = blockIdx.y;
  const int tid = threadIdx.x, w = tid >> 6, lane = tid & 63, lq = lane & 15,
            quad = lane >> 4;
  __shared__ __align__(16) unsigned short xs[2][2][128][40];  // [buf][h/l][row][pad40]
  float4v O[24];
#pragma unroll
  for (int t = 0; t < 24; ++t) O[t] = (float4v){0.f, 0.f, 0.f, 0.f};

  // staging: 512 chunks (128 rows x 4) per h-type; thread -> 1 chunk each
  const int srow = tid >> 2, sc4 = tid & 3;
  uint4 rh, rl;
  auto load_slice = [&](int ks) {
    size_t a = ((size_t)b * ND + n0 + srow) * CD + ks * 32 + sc4 * 8;
    rh = *(const uint4*)(xTh + a);
    rl = *(const uint4*)(xTl + a);
  };
  auto write_slice = [&](int buf) {
    *(uint4*)&xs[buf][0][srow][sc4 * 8] = rh;
    *(uint4*)&xs[buf][1][srow][sc4 * 8] = rl;
  };
  load_slice(0); write_slice(0);
#pragma unroll 1
  for (int ks = 0; ks < 8; ++ks) {
    __syncthreads();
    if (ks < 7) load_slice(ks + 1);
    short8v bxh = *(const short8v*)&xs[ks & 1][0][w * 16 + lq][quad * 8];
    short8v bxl = *(const short8v*)&xs[ks & 1][1][w * 16 + lq][quad * 8];
#pragma unroll
    for (int t = 0; t < 24; ++t) {
      size_t a = (size_t)(t * 16 + lq) * CD + ks * 32 + quad * 8;
      short8v awh = *(const short8v*)(Wch + a);
      short8v awl = *(const short8v*)(Wcl + a);
      O[t] = mfma16(awh, bxh, O[t]);
      O[t] = mfma16(awl, bxh, O[t]);
      O[t] = mfma16(awh, bxl, O[t]);
    }
    if (ks < 7) write_slice((ks + 1) & 1);
  }
  const int n = n0 + w * 16 + lq;
#pragma unroll
  for (int t = 0; t < 24; ++t) {
    if (t < 4) {  // q: hi only
      ushort4 hh;
      hh.x = f2bf(O[t][0]); hh.y = f2bf(O[t][1]);
      hh.z = f2bf(O[t][2]); hh.w = f2bf(O[t][3]);
      *(ushort4*)&qh[((size_t)b * ND + n) * DA + t * 16 + quad * 4] = hh;
    } else if (t < 8) {  // k: hi + lo
      ushort4 hh, ll;
      hh.x = f2bf(O[t][0]); hh.y = f2bf(O[t][1]);
      hh.z = f2bf(O[t][2]); hh.w = f2bf(O[t][3]);
      ll.x = f2bf(O[t][0] - bf2f(hh.x)); ll.y = f2bf(O[t][1] - bf2f(hh.y));
      ll.z = f2bf(O[t][2] - bf2f(hh.z)); ll.w = f2bf(O[t][3] - bf2f(hh.w));
      size_t o = ((size_t)b * ND + n) * DA + (t - 4) * 16 + quad * 4;
      *(ushort4*)&kh[o] = hh;
      *(ushort4*)&kl[o] = ll;
    } else {  // v: transposed bf16 scatter
#pragma unroll
      for (int r = 0; r < 4; ++r) {
        int c = (t - 8) * 16 + quad * 4 + r;
        vT[((size_t)b * CD + c) * ND + n] = f2bf(O[t][r]);
      }
    }
  }
}

// ---------------------------------------------------------------------------
// k_colsum: partial column sums of exp(e), e = qh*kh + qh*kl (2-product).
// n-split grid 512 (2 halves), block owns 128 m-cols x 2048 n-rows.
// ---------------------------------------------------------------------------
__global__ __launch_bounds__(512, 4) void k_colsum(
    const unsigned short* __restrict__ qh, const unsigned short* __restrict__ khp,
    const unsigned short* __restrict__ klp, float* __restrict__ Dp) {
  const int bid = blockIdx.x, b = bid & 7, half = (bid >> 3) & 1,
            m0 = (bid >> 4) * 128;
  const int nbase = half * 2048;
  const int tid = threadIdx.x, w = tid >> 6, lane = tid & 63, lq = lane & 15,
            quad = lane >> 4;
  const int mq = w & 3, nh = w >> 2;
  __shared__ __align__(16) unsigned short qbuf[2][64 * 64];
  __shared__ float Cb[128];
  short8v bkh[2][2], bkl[2][2];
#pragma unroll
  for (int sub = 0; sub < 2; ++sub)
#pragma unroll
    for (int k = 0; k < 2; ++k) {
      size_t a = ((size_t)b * ND + m0 + mq * 32 + sub * 16 + lq) * DA + k * 32 + quad * 8;
      bkh[sub][k] = *(const short8v*)(khp + a);
      bkl[sub][k] = *(const short8v*)(klp + a);
    }
  uint4 sreg;
  const int srow = tid >> 3, sc8 = tid & 7;
  auto load_stage = [&](int nb) {
    sreg = *(const uint4*)(qh + ((size_t)b * ND + nb + srow) * DA + sc8 * 8);
  };
  auto write_stage = [&](int buf) {
    *(uint4*)&qbuf[buf][sw(srow, sc8)] = sreg;
  };
  load_stage(nbase); write_stage(0); load_stage(nbase + 64);
  __syncthreads();
  float cs0 = 0.f, cs1 = 0.f;
#pragma unroll 1
  for (int i = 0; i < 32; ++i) {
    const int cur = i & 1;
#pragma unroll
    for (int s = 0; s < 2; ++s) {
      short8v ah[2];
#pragma unroll
      for (int k = 0; k < 2; ++k)
        ah[k] = *(const short8v*)&qbuf[cur][sw(nh * 32 + s * 16 + lq, k * 4 + quad)];
#pragma unroll
      for (int sub = 0; sub < 2; ++sub) {
        float4v acc = {0.f, 0.f, 0.f, 0.f};
#pragma unroll
        for (int k = 0; k < 2; ++k) {
          acc = mfma16(ah[k], bkh[sub][k], acc);
          acc = mfma16(ah[k], bkl[sub][k], acc);
        }
        float e0 = __expf(acc[0]) + __expf(acc[1]) + __expf(acc[2]) + __expf(acc[3]);
        if (sub == 0) cs0 += e0; else cs1 += e0;
      }
    }
    if (i < 31) { write_stage(1 - cur); if (i < 30) load_stage(nbase + (i + 2) * 64); }
    __syncthreads();
  }
  cs0 += __shfl_down(cs0, 16); cs0 += __shfl_down(cs0, 32);
  cs1 += __shfl_down(cs1, 16); cs1 += __shfl_down(cs1, 32);
  if (nh == 0 && lane < 16) {
    Cb[mq * 32 + lane] = cs0;
    Cb[mq * 32 + 16 + lane] = cs1;
  }
  __syncthreads();
  if (nh == 1 && lane < 16) {
    float t0 = Cb[mq * 32 + lane] + cs0;
    float t1 = Cb[mq * 32 + 16 + lane] + cs1;
    size_t o = (size_t)half * (BD * ND) + (size_t)b * ND + m0 + mq * 32 + lane;
    Dp[o] = t0;
    Dp[o + 16] = t1;
  }
}

// combine halves: Drec = 1/(Dp0+Dp1). grid 32 x 256.
__global__ void k_rcp(const float* __restrict__ Dp, float* __restrict__ Drec) {
  int i = blockIdx.x * 256 + threadIdx.x;
  float4 a = *(const float4*)&Dp[(size_t)i * 4];
  float4 c = *(const float4*)&Dp[(size_t)(BD * ND) + (size_t)i * 4];
  float4 r;
  r.x = 1.f / (a.x + c.x); r.y = 1.f / (a.y + c.y);
  r.z = 1.f / (a.z + c.z); r.w = 1.f / (a.w + c.w);
  *(float4*)&Drec[(size_t)i * 4] = r;
}

// ---------------------------------------------------------------------------
// k_attn: flash main loop. BQ=64, grid 512 -> 2 blocks/CU (LDS 72KB,
// launch_bounds(512,4) caps VGPR at 128). 8 waves: wave (nq in 0..3: 16 n,
// ch in 0..1: m-half for e / c-half for PV).
//  - e = qh*kh + qh*kl (2-product); k frags straight from L2.
//  - vbuf (256c x 64m) double-buffered via global_load_lds, DMA for i+1
//    issued at PV(i) start, drained by barrier B(i) -> one phase of slack.
//  - single Pb + 2 barriers/iter.
//  - row sums S accumulated in registers during e, reduced by lq-butterfly +
//    LDS combine at the end (no ones-column -> vT is just 256 rows).
// NOTE: all accumulator loops compile-time unrolled, constant O indices
// (runtime trip counts demote O[] to scratch -> R3: 2.9 GB HBM writes).
// ---------------------------------------------------------------------------
__global__ __launch_bounds__(512, 4) void k_attn(
    const unsigned short* __restrict__ qh, const unsigned short* __restrict__ khp,
    const unsigned short* __restrict__ klp, const unsigned short* __restrict__ vT,
    const float* __restrict__ Drec, unsigned short* xhy,
    const unsigned short* __restrict__ xTl) {
  const int bid = blockIdx.x, b = bid & 7, n0 = (bid >> 3) * 64;
  const int tid = threadIdx.x, w = tid >> 6, lane = tid & 63, lq = lane & 15,
            quad = lane >> 4;
  const int nq = w & 3, ch = w >> 2;
  __shared__ __align__(16) unsigned char arena[2 * 32768 + 8192];
  unsigned short* vbuf0 = (unsigned short*)arena;
  unsigned short* vbuf1 = (unsigned short*)(arena + 32768);
  unsigned short* Pb    = (unsigned short*)(arena + 65536);
  float* Sb             = (float*)(arena + 65536);  // alias Pb; used after Pb dead

  // q A-frags (hi only), resident
  short8v aq[2];
#pragma unroll
  for (int k = 0; k < 2; ++k)
    aq[k] = *(const short8v*)(qh + ((size_t)b * ND + n0 + nq * 16 + lq) * DA +
                              k * 32 + quad * 8);
  float4v O[8];
#pragma unroll
  for (int t = 0; t < 8; ++t) O[t] = (float4v){0.f, 0.f, 0.f, 0.f};
  float rs[4] = {0.f, 0.f, 0.f, 0.f};

  // async vT staging: 2048 chunks, 4 per thread, swizzle baked into source
  auto stageV = [&](int mt, unsigned short* base) {
#pragma unroll
    for (int j = 0; j < 4; ++j) {
      int cidx = tid + j * 512;
      int row = cidx >> 3, ckpos = cidx & 7;
      const unsigned short* src =
          vT + ((size_t)b * CD + row) * ND + mt * 64 + ((ckpos ^ (row & 7)) << 3);
      gld16(src, base + (size_t)(w * 64 + j * 512) * 8);
    }
  };

  stageV(0, vbuf0);
  __syncthreads();  // not strictly needed for vbuf (drained at barrier A of i=0)

#pragma unroll 1
  for (int i = 0; i < 64; ++i) {
    // ---- e(i): load k frags (L2) + Drec, 2-product QK^T -> P in Pb ----
    const int mg0 = (i << 6) + ch * 32;
    short8v kch[2][2], kcl[2][2];
#pragma unroll
    for (int sub = 0; sub < 2; ++sub)
#pragma unroll
      for (int k = 0; k < 2; ++k) {
        size_t a = ((size_t)b * ND + mg0 + sub * 16 + lq) * DA + k * 32 + quad * 8;
        kch[sub][k] = *(const short8v*)(khp + a);
        kcl[sub][k] = *(const short8v*)(klp + a);
      }
    float dr[2];
#pragma unroll
    for (int sub = 0; sub < 2; ++sub)
      dr[sub] = Drec[(size_t)b * ND + mg0 + sub * 16 + lq];
#pragma unroll
    for (int sub = 0; sub < 2; ++sub) {
      float4v acc = {0.f, 0.f, 0.f, 0.f};
#pragma unroll
      for (int k = 0; k < 2; ++k) {
        acc = mfma16(aq[k], kch[sub][k], acc);
        acc = mfma16(aq[k], kcl[sub][k], acc);
      }
      const int m_loc = ch * 32 + sub * 16 + lq;
#pragma unroll
      for (int r = 0; r < 4; ++r) {
        float p = __expf(acc[r]) * dr[sub];
        rs[r] += p;
        const int n_loc = nq * 16 + quad * 4 + r;
        union { float f; unsigned int u; } pu; pu.f = p;
        Pb[n_loc * 64 + ((((m_loc >> 3) ^ (n_loc & 7)) << 3) | (m_loc & 7))] =
            (unsigned short)(pu.u >> 16);  // truncation: bias cancels in P/S
      }
    }
    __syncthreads();  // barrier A: P visible; DMA(i) (issued in PV(i-1)) drained
    // ---- PV(i): issue DMA(i+1), then O[c][n] += vT * P ----
    unsigned short* vc = (i & 1) ? vbuf1 : vbuf0;
    if (i < 63) stageV(i + 1, (i & 1) ? vbuf0 : vbuf1);
    short8v ap[2];
#pragma unroll
    for (int k = 0; k < 2; ++k)
      ap[k] = *(const short8v*)&Pb[sw(nq * 16 + lq, k * 4 + quad)];
#pragma unroll
    for (int t = 0; t < 8; ++t) {
      const int trow = (ch * 8 + t) * 16 + lq;
#pragma unroll
      for (int k = 0; k < 2; ++k) {
        short8v bv = *(const short8v*)&vc[sw(trow, k * 4 + quad)];
        O[t] = mfma16(bv, ap[k], O[t]);
      }
    }
    __syncthreads();  // barrier B: PV done before e(i+1) rewrites Pb
  }
  // ---- S reduction: butterfly over lq, combine ch halves in LDS ----
#pragma unroll
  for (int r = 0; r < 4; ++r) {
    rs[r] += __shfl_xor(rs[r], 1);
    rs[r] += __shfl_xor(rs[r], 2);
    rs[r] += __shfl_xor(rs[r], 4);
    rs[r] += __shfl_xor(rs[r], 8);
  }
  if (ch == 0 && lq == 0) {
#pragma unroll
    for (int r = 0; r < 4; ++r) Sb[nq * 16 + quad * 4 + r] = rs[r];
  }
  __syncthreads();
  if (ch == 1 && lq == 0) {
#pragma unroll
    for (int r = 0; r < 4; ++r) Sb[nq * 16 + quad * 4 + r] += rs[r];
  }
  __syncthreads();
  const float rsc = 1.0f / (1e-9f + Sb[nq * 16 + lq]);
  // ---- y = x - O/S, in place over xTh (lane owns 4 consecutive c, fixed n)
  const int n = n0 + nq * 16 + lq;
#pragma unroll
  for (int t = 0; t < 8; ++t) {
    const int cb = (ch * 8 + t) * 16 + quad * 4;
    const size_t off = ((size_t)b * ND + n) * CD + cb;
    ushort4 h4 = *(const ushort4*)&xhy[off];
    ushort4 l4 = *(const ushort4*)&xTl[off];
    ushort4 o4;
    o4.x = f2bf(bf2f(h4.x) + bf2f(l4.x) - O[t][0] * rsc);
    o4.y = f2bf(bf2f(h4.y) + bf2f(l4.y) - O[t][1] * rsc);
    o4.z = f2bf(bf2f(h4.z) + bf2f(l4.z) - O[t][2] * rsc);
    o4.w = f2bf(bf2f(h4.w) + bf2f(l4.w) - O[t][3] * rsc);
    *(ushort4*)&xhy[off] = o4;
  }
}

// ---------------------------------------------------------------------------
// k_final: h = Wp . y (bf16 MFMA); out = relu(BN(h)) + x.
// ---------------------------------------------------------------------------
__global__ __launch_bounds__(256) void k_final(const unsigned short* __restrict__ y,
                                               const unsigned short* __restrict__ Wpb,
                                               const float* __restrict__ x,
                                               const float* __restrict__ gamma,
                                               const float* __restrict__ beta,
                                               const float* __restrict__ mean,
                                               const float* __restrict__ var,
                                               float* __restrict__ out) {
  const int bid = blockIdx.x;
  const int b = bid & 7;
  const int rem = bid >> 3;
  const int n0 = (rem & 63) * 64;
  const int d0 = (rem >> 6) * 64;
  const int tid = threadIdx.x;
  const int wave = tid >> 6, lane = tid & 63, lq = lane & 15, quad = lane >> 4;
  const int dw = d0 + wave * 16;
  float4v O[4];
#pragma unroll
  for (int s = 0; s < 4; ++s) O[s] = (float4v){0.f, 0.f, 0.f, 0.f};
#pragma unroll
  for (int chh = 0; chh < 8; ++chh) {
    const size_t ab = (size_t)(dw + lq) * CD + chh * 32 + quad * 8;
    short8v a0 = *(const short8v*)(Wpb + ab);
#pragma unroll
    for (int s = 0; s < 4; ++s) {
      const size_t bb = ((size_t)b * ND + n0 + s * 16 + lq) * CD + chh * 32 + quad * 8;
      short8v bv = *(const short8v*)(y + bb);
      O[s] = mfma16(a0, bv, O[s]);
    }
  }
#pragma unroll
  for (int r = 0; r < 4; ++r) {
    const int d = dw + quad * 4 + r;
    const float inv  = gamma[d] / sqrtf(var[d] + 1e-5f);
    const float bias = beta[d] - mean[d] * inv;
#pragma unroll
    for (int s = 0; s < 4; ++s) {
      const int n = n0 + s * 16 + lq;
      const size_t oi = ((size_t)b * CD + d) * ND + n;
      out[oi] = fmaxf(O[s][r] * inv + bias, 0.f) + x[oi];
    }
  }
}

extern "C" void kernel_launch(void* const* d_in, const int* in_sizes, int n_in,
                              void* d_out, int out_size, void* d_ws, size_t ws_size,
                              hipStream_t stream) {
  const float* x     = (const float*)d_in[0];
  const float* Wq    = (const float*)d_in[1];
  const float* Wk    = (const float*)d_in[2];
  const float* Wv    = (const float*)d_in[3];
  const float* Wp    = (const float*)d_in[4];
  const float* gamma = (const float*)d_in[5];
  const float* beta  = (const float*)d_in[6];
  const float* mean  = (const float*)d_in[7];
  const float* var   = (const float*)d_in[8];
  float* out = (float*)d_out;

  char* wsp = (char*)d_ws;
  unsigned short* qhp = (unsigned short*)wsp; wsp += (size_t)BD * ND * DA * 2;
  unsigned short* khp = (unsigned short*)wsp; wsp += (size_t)BD * ND * DA * 2;
  unsigned short* klp = (unsigned short*)wsp; wsp += (size_t)BD * ND * DA * 2;
  unsigned short* vT  = (unsigned short*)wsp; wsp += (size_t)BD * CD * ND * 2;
  unsigned short* xTh = (unsigned short*)wsp; wsp += (size_t)BD * ND * CD * 2;  // aliased as y
  unsigned short* xTl = (unsigned short*)wsp; wsp += (size_t)BD * ND * CD * 2;
  unsigned short* Wch = (unsigned short*)wsp; wsp += (size_t)384 * 256 * 2;
  unsigned short* Wcl = (unsigned short*)wsp; wsp += (size_t)384 * 256 * 2;
  unsigned short* Wph = (unsigned short*)wsp; wsp += (size_t)256 * 256 * 2;
  unsigned short* Wpl = (unsigned short*)wsp; wsp += (size_t)256 * 256 * 2;
  float* Drec = (float*)wsp; wsp += (size_t)BD * ND * 4;
  float* Dp   = (float*)wsp; wsp += (size_t)2 * BD * ND * 4;
  unsigned short* y = xTh;  // xTh consumed+overwritten by k_attn epilogue

  dim3 blk(256), blk5(512);
  k_prep<<<dim3(ND / 64, CD / 64, BD), blk, 0, stream>>>(x, xTh, xTl);
  k_prepW<<<dim3(160), blk, 0, stream>>>(Wq, Wk, Wv, Wp, Wch, Wcl, Wph, Wpl);
  k_proj<<<dim3(ND / 128, BD), blk5, 0, stream>>>(xTh, xTl, Wch, Wcl, qhp, khp,
                                                  klp, vT);
  k_colsum<<<dim3(512), blk5, 0, stream>>>(qhp, khp, klp, Dp);
  k_rcp<<<dim3(32), blk, 0, stream>>>(Dp, Drec);
  k_attn<<<dim3(512), blk5, 0, stream>>>(qhp, khp, klp, vT, Drec, y, xTl);
  k_final<<<dim3(2048), blk, 0, stream>>>(y, Wph, x, gamma, beta, mean, var, out);
}

// Round 7
// 511.962 us; speedup vs baseline: 1.1359x; 1.1359x over previous
//
#include <hip/hip_runtime.h>
#include <math.h>

#define BD 8
#define CD 256
#define ND 4096
#define DA 64

typedef __attribute__((ext_vector_type(8))) short short8v;
typedef __attribute__((ext_vector_type(4))) float float4v;

static __device__ __forceinline__ float4v mfma16(short8v a, short8v b, float4v c) {
  return __builtin_amdgcn_mfma_f32_16x16x32_bf16(a, b, c, 0, 0, 0);
}
static __device__ __forceinline__ unsigned short f2bf(float f) {
  union { float f; unsigned int u; } v; v.f = f;
  return (unsigned short)((v.u + 0x7fffu + ((v.u >> 16) & 1u)) >> 16);
}
static __device__ __forceinline__ float bf2f(unsigned short h) {
  union { unsigned int u; float f; } v; v.u = (unsigned int)h << 16;
  return v.f;
}
// XOR-swizzled LDS offset (ushort units) for rows of 64 bf16 (8 x 16B chunks).
static __device__ __forceinline__ int sw(int row, int c8) {
  return row * 64 + (((c8) ^ (row & 7)) << 3);
}
typedef const __attribute__((address_space(1))) unsigned int g_u32;
typedef __attribute__((address_space(3))) unsigned int l_u32;
static __device__ __forceinline__ void gld16(const void* g, void* l) {
  __builtin_amdgcn_global_load_lds((g_u32*)g, (l_u32*)l, 16, 0, 0);
}

// ---------------------------------------------------------------------------
// k_prep: x [b][c][n] fp32 -> xTh/xTl [b][n][256] split bf16 (transposed).
// ---------------------------------------------------------------------------
__global__ __launch_bounds__(256) void k_prep(const float* __restrict__ x,
                                              unsigned short* __restrict__ xTh,
                                              unsigned short* __restrict__ xTl) {
  const int n0 = blockIdx.x * 64, c0 = blockIdx.y * 64, b = blockIdx.z;
  __shared__ float Xs[64][68];
  const int tid = threadIdx.x;
  const int r0 = tid >> 4, col4 = (tid & 15) * 4;
#pragma unroll
  for (int j = 0; j < 4; ++j) {
    int r = r0 + j * 16;
    *(float4*)&Xs[r][col4] =
        *(const float4*)&x[((size_t)(b * CD + c0 + r)) * ND + n0 + col4];
  }
  __syncthreads();
  const int n = tid >> 2, cg = (tid & 3) * 16;
  unsigned short h[16], l[16];
#pragma unroll
  for (int j = 0; j < 16; ++j) {
    float v = Xs[cg + j][n];
    h[j] = f2bf(v);
    l[j] = f2bf(v - bf2f(h[j]));
  }
  size_t o = ((size_t)b * ND + n0 + n) * CD + c0 + cg;
#pragma unroll
  for (int j = 0; j < 4; ++j) {
    *(ushort4*)&xTh[o + j * 4] = *(ushort4*)&h[j * 4];
    *(ushort4*)&xTl[o + j * 4] = *(ushort4*)&l[j * 4];
  }
}

// ---------------------------------------------------------------------------
// k_prepW: split weights fp32 -> bf16 hi/lo. Wch/Wcl = [Wq;Wk;Wv] rows 0..383.
// ---------------------------------------------------------------------------
__global__ void k_prepW(const float* __restrict__ Wq, const float* __restrict__ Wk,
                        const float* __restrict__ Wv, const float* __restrict__ Wp,
                        unsigned short* Wch, unsigned short* Wcl,
                        unsigned short* Wph, unsigned short* Wpl) {
  int i = blockIdx.x * 256 + threadIdx.x;  // 640 rows x 64 float4
  int row = i >> 6, c4 = (i & 63) * 4;
  const float* src; unsigned short *dh, *dl; int r, drow;
  if (row < 64)       { src = Wq; r = row;       dh = Wch; dl = Wcl; drow = row; }
  else if (row < 128) { src = Wk; r = row - 64;  dh = Wch; dl = Wcl; drow = row; }
  else if (row < 384) { src = Wv; r = row - 128; dh = Wch; dl = Wcl; drow = row; }
  else                { src = Wp; r = row - 384; dh = Wph; dl = Wpl; drow = row - 384; }
  float4 f = *(const float4*)&src[(size_t)r * 256 + c4];
  ushort4 hh, ll;
  hh.x = f2bf(f.x); hh.y = f2bf(f.y); hh.z = f2bf(f.z); hh.w = f2bf(f.w);
  ll.x = f2bf(f.x - bf2f(hh.x)); ll.y = f2bf(f.y - bf2f(hh.y));
  ll.z = f2bf(f.z - bf2f(hh.z)); ll.w = f2bf(f.w - bf2f(hh.w));
  *(ushort4*)&dh[(size_t)drow * 256 + c4] = hh;
  *(ushort4*)&dl[(size_t)drow * 256 + c4] = ll;
}

// ---------------------------------------------------------------------------
// k_proj: MERGED q/k/v projection (reads xT once, LDS k-slices, 3-product).
// grid (ND/128, B), 512 thr. q: hi only; k: hi+lo; v: transposed bf16.
// ---------------------------------------------------------------------------
__global__ __launch_bounds__(512) void k_proj(
    const unsigned short* __restrict__ xTh, const unsigned short* __restrict__ xTl,
    const unsigned short* __restrict__ Wch, const unsigned short* __restrict__ Wcl,
    unsigned short* __restrict__ qh, unsigned short* __restrict__ kh,
    unsigned short* __restrict__ kl, unsigned short* __restrict__ vT) {
  const int n0 = blockIdx.x * 128, b = blockIdx.y;
  const int tid = threadIdx.x, w = tid >> 6, lane = tid & 63, lq = lane & 15,
            quad = lane >> 4;
  __shared__ __align__(16) unsigned short xs[2][2][128][40];
  float4v O[24];
#pragma unroll
  for (int t = 0; t < 24; ++t) O[t] = (float4v){0.f, 0.f, 0.f, 0.f};

  const int srow = tid >> 2, sc4 = tid & 3;
  uint4 rh, rl;
  auto load_slice = [&](int ks) {
    size_t a = ((size_t)b * ND + n0 + srow) * CD + ks * 32 + sc4 * 8;
    rh = *(const uint4*)(xTh + a);
    rl = *(const uint4*)(xTl + a);
  };
  auto write_slice = [&](int buf) {
    *(uint4*)&xs[buf][0][srow][sc4 * 8] = rh;
    *(uint4*)&xs[buf][1][srow][sc4 * 8] = rl;
  };
  load_slice(0); write_slice(0);
#pragma unroll 1
  for (int ks = 0; ks < 8; ++ks) {
    __syncthreads();
    if (ks < 7) load_slice(ks + 1);
    short8v bxh = *(const short8v*)&xs[ks & 1][0][w * 16 + lq][quad * 8];
    short8v bxl = *(const short8v*)&xs[ks & 1][1][w * 16 + lq][quad * 8];
#pragma unroll
    for (int t = 0; t < 24; ++t) {
      size_t a = (size_t)(t * 16 + lq) * CD + ks * 32 + quad * 8;
      short8v awh = *(const short8v*)(Wch + a);
      short8v awl = *(const short8v*)(Wcl + a);
      O[t] = mfma16(awh, bxh, O[t]);
      O[t] = mfma16(awl, bxh, O[t]);
      O[t] = mfma16(awh, bxl, O[t]);
    }
    if (ks < 7) write_slice((ks + 1) & 1);
  }
  const int n = n0 + w * 16 + lq;
#pragma unroll
  for (int t = 0; t < 24; ++t) {
    if (t < 4) {
      ushort4 hh;
      hh.x = f2bf(O[t][0]); hh.y = f2bf(O[t][1]);
      hh.z = f2bf(O[t][2]); hh.w = f2bf(O[t][3]);
      *(ushort4*)&qh[((size_t)b * ND + n) * DA + t * 16 + quad * 4] = hh;
    } else if (t < 8) {
      ushort4 hh, ll;
      hh.x = f2bf(O[t][0]); hh.y = f2bf(O[t][1]);
      hh.z = f2bf(O[t][2]); hh.w = f2bf(O[t][3]);
      ll.x = f2bf(O[t][0] - bf2f(hh.x)); ll.y = f2bf(O[t][1] - bf2f(hh.y));
      ll.z = f2bf(O[t][2] - bf2f(hh.z)); ll.w = f2bf(O[t][3] - bf2f(hh.w));
      size_t o = ((size_t)b * ND + n) * DA + (t - 4) * 16 + quad * 4;
      *(ushort4*)&kh[o] = hh;
      *(ushort4*)&kl[o] = ll;
    } else {
#pragma unroll
      for (int r = 0; r < 4; ++r) {
        int c = (t - 8) * 16 + quad * 4 + r;
        vT[((size_t)b * CD + c) * ND + n] = f2bf(O[t][r]);
      }
    }
  }
}

// ---------------------------------------------------------------------------
// k_colsum: partial column sums of exp(e), e = qh*kh + qh*kl (2-product).
// 1 barrier/iter; q-tiles staged via async global_load_lds, TRIPLE-buffered
// so the DMA crosses two barriers before its drain matters.
// grid 512 (n-split halves), block owns 128 m x 2048 n.
// ---------------------------------------------------------------------------
__global__ __launch_bounds__(512, 4) void k_colsum(
    const unsigned short* __restrict__ qh, const unsigned short* __restrict__ khp,
    const unsigned short* __restrict__ klp, float* __restrict__ Dp) {
  const int bid = blockIdx.x, b = bid & 7, half = (bid >> 3) & 1,
            m0 = (bid >> 4) * 128;
  const int nbase = half * 2048;
  const int tid = threadIdx.x, w = tid >> 6, lane = tid & 63, lq = lane & 15,
            quad = lane >> 4;
  const int mq = w & 3, nh = w >> 2;
  __shared__ __align__(16) unsigned short qbuf[3][4096];  // 64n x 64d swizzled
  __shared__ float Cb[128];
  short8v bkh[2][2], bkl[2][2];
#pragma unroll
  for (int sub = 0; sub < 2; ++sub)
#pragma unroll
    for (int k = 0; k < 2; ++k) {
      size_t a = ((size_t)b * ND + m0 + mq * 32 + sub * 16 + lq) * DA + k * 32 + quad * 8;
      bkh[sub][k] = *(const short8v*)(khp + a);
      bkl[sub][k] = *(const short8v*)(klp + a);
    }
  // async staging: 512 chunks/tile, 1 per thread; swizzle baked into source
  const int srow = w * 8 + (lane >> 3), sck = lane & 7;
  auto stageQ = [&](int it, int qn) {
    const unsigned short* src = qh + ((size_t)b * ND + nbase + it * 64 + srow) * DA +
                                ((sck ^ (srow & 7)) << 3);
    gld16(src, &qbuf[qn][0] + (size_t)w * 512);
  };
  stageQ(0, 0);
  __syncthreads();
  float cs0 = 0.f, cs1 = 0.f;
  int vs = 1, vc = 0;
#pragma unroll 1
  for (int i = 0; i < 32; ++i) {
    if (i < 31) { stageQ(i + 1, vs); vs = (vs + 1 == 3) ? 0 : vs + 1; }
#pragma unroll
    for (int s = 0; s < 2; ++s) {
      short8v ah[2];
#pragma unroll
      for (int k = 0; k < 2; ++k)
        ah[k] = *(const short8v*)&qbuf[vc][sw(nh * 32 + s * 16 + lq, k * 4 + quad)];
#pragma unroll
      for (int sub = 0; sub < 2; ++sub) {
        float4v acc = {0.f, 0.f, 0.f, 0.f};
#pragma unroll
        for (int k = 0; k < 2; ++k) {
          acc = mfma16(ah[k], bkh[sub][k], acc);
          acc = mfma16(ah[k], bkl[sub][k], acc);
        }
        float e0 = __expf(acc[0]) + __expf(acc[1]) + __expf(acc[2]) + __expf(acc[3]);
        if (sub == 0) cs0 += e0; else cs1 += e0;
      }
    }
    vc = (vc + 1 == 3) ? 0 : vc + 1;
    __syncthreads();
  }
  cs0 += __shfl_down(cs0, 16); cs0 += __shfl_down(cs0, 32);
  cs1 += __shfl_down(cs1, 16); cs1 += __shfl_down(cs1, 32);
  if (nh == 0 && lane < 16) {
    Cb[mq * 32 + lane] = cs0;
    Cb[mq * 32 + 16 + lane] = cs1;
  }
  __syncthreads();
  if (nh == 1 && lane < 16) {
    float t0 = Cb[mq * 32 + lane] + cs0;
    float t1 = Cb[mq * 32 + 16 + lane] + cs1;
    size_t o = (size_t)half * (BD * ND) + (size_t)b * ND + m0 + mq * 32 + lane;
    Dp[o] = t0;
    Dp[o + 16] = t1;
  }
}

// combine halves: Drec = 1/(Dp0+Dp1). grid 32 x 256.
__global__ void k_rcp(const float* __restrict__ Dp, float* __restrict__ Drec) {
  int i = blockIdx.x * 256 + threadIdx.x;
  float4 a = *(const float4*)&Dp[(size_t)i * 4];
  float4 c = *(const float4*)&Dp[(size_t)(BD * ND) + (size_t)i * 4];
  float4 r;
  r.x = 1.f / (a.x + c.x); r.y = 1.f / (a.y + c.y);
  r.z = 1.f / (a.z + c.z); r.w = 1.f / (a.w + c.w);
  *(float4*)&Drec[(size_t)i * 4] = r;
}

// ---------------------------------------------------------------------------
// k_attn: flash main loop, 1 barrier/iter, BQ=128, BM=64, grid 256 (1 blk/CU).
// Body(i) = [PV(i-1); issue DMA(i+1) + kload(i+1) + Drec(i+1); e(i); barrier].
// The vT DMA issued in body(i) is consumed by PV(i) in body(i+1) -- it crosses
// two full phases before its draining barrier matters -> triple-buffered vbuf
// (writer/reader always differ mod 3; race-checked). k B-frags prefetched one
// iter ahead from L2. Pb double-buffered. e = 2-product split-bf16.
// NOTE: all accumulator loops compile-time unrolled, constant O indices
// (runtime trip counts demote O[] to scratch -> R3: 2.9 GB HBM writes).
// ---------------------------------------------------------------------------
__global__ __launch_bounds__(512, 2) void k_attn(
    const unsigned short* __restrict__ qh, const unsigned short* __restrict__ khp,
    const unsigned short* __restrict__ klp, const unsigned short* __restrict__ vT,
    const float* __restrict__ Drec, unsigned short* xhy,
    const unsigned short* __restrict__ xTl) {
  const int bid = blockIdx.x, b = bid & 7, n0 = (bid >> 3) * 128;
  const int tid = threadIdx.x, w = tid >> 6, lane = tid & 63, lq = lane & 15,
            quad = lane >> 4;
  const int nq = w & 3, ch = w >> 2;
  __shared__ __align__(16) unsigned short vbuf[3][16384];  // 256c x 64m swizzled
  __shared__ __align__(16) unsigned short Pb[2][8192];     // 128n x 64m swizzled
  __shared__ float Sb[128];

  // q A-frags (hi only), resident
  short8v aq[2][2];
#pragma unroll
  for (int s = 0; s < 2; ++s)
#pragma unroll
    for (int k = 0; k < 2; ++k)
      aq[s][k] = *(const short8v*)(qh + ((size_t)b * ND + n0 + nq * 32 + s * 16 + lq) * DA +
                                   k * 32 + quad * 8);
  float4v O[2][8];
#pragma unroll
  for (int s = 0; s < 2; ++s)
#pragma unroll
    for (int t = 0; t < 8; ++t) O[s][t] = (float4v){0.f, 0.f, 0.f, 0.f};
  float rs[2][4] = {{0.f, 0.f, 0.f, 0.f}, {0.f, 0.f, 0.f, 0.f}};

  // async vT staging: 2048 chunks, 4/thread, swizzle baked into source
  auto stageV = [&](int mt, int vn) {
    unsigned short* base = &vbuf[vn][0];
#pragma unroll
    for (int j = 0; j < 4; ++j) {
      int cidx = tid + j * 512;
      int row = cidx >> 3, ckpos = cidx & 7;
      const unsigned short* src =
          vT + ((size_t)b * CD + row) * ND + mt * 64 + ((ckpos ^ (row & 7)) << 3);
      gld16(src, base + (size_t)(w * 64 + j * 512) * 8);
    }
  };
  short8v kc[8], kn[8];
  auto kload = [&](short8v* dst, int mt) {
#pragma unroll
    for (int sub = 0; sub < 2; ++sub)
#pragma unroll
      for (int k = 0; k < 2; ++k) {
        size_t a = ((size_t)b * ND + mt * 64 + ch * 32 + sub * 16 + lq) * DA +
                   k * 32 + quad * 8;
        dst[sub * 4 + k * 2 + 0] = *(const short8v*)(khp + a);
        dst[sub * 4 + k * 2 + 1] = *(const short8v*)(klp + a);
      }
  };
  auto doPV = [&](const unsigned short* Pc, const unsigned short* vc) {
    short8v ap[2][2];
#pragma unroll
    for (int s = 0; s < 2; ++s)
#pragma unroll
      for (int k = 0; k < 2; ++k)
        ap[s][k] = *(const short8v*)&Pc[sw(nq * 32 + s * 16 + lq, k * 4 + quad)];
#pragma unroll
    for (int t = 0; t < 8; ++t) {
      const int trow = (ch * 8 + t) * 16 + lq;
#pragma unroll
      for (int k = 0; k < 2; ++k) {
        short8v bv = *(const short8v*)&vc[sw(trow, k * 4 + quad)];
#pragma unroll
        for (int s = 0; s < 2; ++s) O[s][t] = mfma16(bv, ap[s][k], O[s][t]);
      }
    }
  };

  float drc[2], drn[2];
  stageV(0, 0);
  kload(kc, 0);
#pragma unroll
  for (int sub = 0; sub < 2; ++sub)
    drc[sub] = Drec[(size_t)b * ND + ch * 32 + sub * 16 + lq];

  int vs = 1, vp = 0;
#pragma unroll 1
  for (int i = 0; i < 64; ++i) {
    if (i > 0) {
      doPV(&Pb[(i - 1) & 1][0], &vbuf[vp][0]);
      vp = (vp + 1 == 3) ? 0 : vp + 1;
    }
    if (i < 63) {
      stageV(i + 1, vs);
      vs = (vs + 1 == 3) ? 0 : vs + 1;
      kload(kn, i + 1);
#pragma unroll
      for (int sub = 0; sub < 2; ++sub)
        drn[sub] = Drec[(size_t)b * ND + (i + 1) * 64 + ch * 32 + sub * 16 + lq];
    }
    // ---- e(i): 2-product QK^T -> P (truncated bf16) into Pb[i&1] ----
    unsigned short* Pcur = &Pb[i & 1][0];
#pragma unroll
    for (int sub = 0; sub < 2; ++sub) {
      const int m_loc = ch * 32 + sub * 16 + lq;
#pragma unroll
      for (int s = 0; s < 2; ++s) {
        float4v acc = {0.f, 0.f, 0.f, 0.f};
#pragma unroll
        for (int k = 0; k < 2; ++k) {
          acc = mfma16(aq[s][k], kc[sub * 4 + k * 2 + 0], acc);
          acc = mfma16(aq[s][k], kc[sub * 4 + k * 2 + 1], acc);
        }
#pragma unroll
        for (int r = 0; r < 4; ++r) {
          float p = __expf(acc[r]) * drc[sub];
          rs[s][r] += p;
          const int n_loc = nq * 32 + s * 16 + quad * 4 + r;
          union { float f; unsigned int u; } pu; pu.f = p;
          Pcur[n_loc * 64 + ((((m_loc >> 3) ^ (n_loc & 7)) << 3) | (m_loc & 7))] =
              (unsigned short)(pu.u >> 16);  // truncation: bias cancels in P/S
        }
      }
    }
    if (i < 63) {
#pragma unroll
      for (int t = 0; t < 8; ++t) kc[t] = kn[t];
      drc[0] = drn[0]; drc[1] = drn[1];
    }
    __syncthreads();  // P(i) visible; drains DMA(i+1) (consumed next body)
  }
  doPV(&Pb[1][0], &vbuf[vp][0]);  // PV(63); 63&1 == 1

  // ---- S reduction: butterfly over lq, combine ch halves in LDS ----
#pragma unroll
  for (int s = 0; s < 2; ++s)
#pragma unroll
    for (int r = 0; r < 4; ++r) {
      rs[s][r] += __shfl_xor(rs[s][r], 1);
      rs[s][r] += __shfl_xor(rs[s][r], 2);
      rs[s][r] += __shfl_xor(rs[s][r], 4);
      rs[s][r] += __shfl_xor(rs[s][r], 8);
    }
  if (ch == 0 && lq == 0) {
#pragma unroll
    for (int s = 0; s < 2; ++s)
#pragma unroll
      for (int r = 0; r < 4; ++r) Sb[nq * 32 + s * 16 + quad * 4 + r] = rs[s][r];
  }
  __syncthreads();
  if (ch == 1 && lq == 0) {
#pragma unroll
    for (int s = 0; s < 2; ++s)
#pragma unroll
      for (int r = 0; r < 4; ++r) Sb[nq * 32 + s * 16 + quad * 4 + r] += rs[s][r];
  }
  __syncthreads();
  float rsc[2];
#pragma unroll
  for (int s = 0; s < 2; ++s)
    rsc[s] = 1.0f / (1e-9f + Sb[nq * 32 + s * 16 + lq]);
  // ---- y = x - O/S, in place over xTh (lane: 4 consecutive c, fixed n) ----
#pragma unroll
  for (int t = 0; t < 8; ++t) {
    const int cb = (ch * 8 + t) * 16 + quad * 4;
#pragma unroll
    for (int s = 0; s < 2; ++s) {
      const int n = n0 + nq * 32 + s * 16 + lq;
      const size_t off = ((size_t)b * ND + n) * CD + cb;
      ushort4 h4 = *(const ushort4*)&xhy[off];
      ushort4 l4 = *(const ushort4*)&xTl[off];
      ushort4 o4;
      o4.x = f2bf(bf2f(h4.x) + bf2f(l4.x) - O[s][t][0] * rsc[s]);
      o4.y = f2bf(bf2f(h4.y) + bf2f(l4.y) - O[s][t][1] * rsc[s]);
      o4.z = f2bf(bf2f(h4.z) + bf2f(l4.z) - O[s][t][2] * rsc[s]);
      o4.w = f2bf(bf2f(h4.w) + bf2f(l4.w) - O[s][t][3] * rsc[s]);
      *(ushort4*)&xhy[off] = o4;
    }
  }
}

// ---------------------------------------------------------------------------
// k_final: h = Wp . y (bf16 MFMA); out = relu(BN(h)) + x.
// ---------------------------------------------------------------------------
__global__ __launch_bounds__(256) void k_final(const unsigned short* __restrict__ y,
                                               const unsigned short* __restrict__ Wpb,
                                               const float* __restrict__ x,
                                               const float* __restrict__ gamma,
                                               const float* __restrict__ beta,
                                               const float* __restrict__ mean,
                                               const float* __restrict__ var,
                                               float* __restrict__ out) {
  const int bid = blockIdx.x;
  const int b = bid & 7;
  const int rem = bid >> 3;
  const int n0 = (rem & 63) * 64;
  const int d0 = (rem >> 6) * 64;
  const int tid = threadIdx.x;
  const int wave = tid >> 6, lane = tid & 63, lq = lane & 15, quad = lane >> 4;
  const int dw = d0 + wave * 16;
  float4v O[4];
#pragma unroll
  for (int s = 0; s < 4; ++s) O[s] = (float4v){0.f, 0.f, 0.f, 0.f};
#pragma unroll
  for (int chh = 0; chh < 8; ++chh) {
    const size_t ab = (size_t)(dw + lq) * CD + chh * 32 + quad * 8;
    short8v a0 = *(const short8v*)(Wpb + ab);
#pragma unroll
    for (int s = 0; s < 4; ++s) {
      const size_t bb = ((size_t)b * ND + n0 + s * 16 + lq) * CD + chh * 32 + quad * 8;
      short8v bv = *(const short8v*)(y + bb);
      O[s] = mfma16(a0, bv, O[s]);
    }
  }
#pragma unroll
  for (int r = 0; r < 4; ++r) {
    const int d = dw + quad * 4 + r;
    const float inv  = gamma[d] / sqrtf(var[d] + 1e-5f);
    const float bias = beta[d] - mean[d] * inv;
#pragma unroll
    for (int s = 0; s < 4; ++s) {
      const int n = n0 + s * 16 + lq;
      const size_t oi = ((size_t)b * CD + d) * ND + n;
      out[oi] = fmaxf(O[s][r] * inv + bias, 0.f) + x[oi];
    }
  }
}

extern "C" void kernel_launch(void* const* d_in, const int* in_sizes, int n_in,
                              void* d_out, int out_size, void* d_ws, size_t ws_size,
                              hipStream_t stream) {
  const float* x     = (const float*)d_in[0];
  const float* Wq    = (const float*)d_in[1];
  const float* Wk    = (const float*)d_in[2];
  const float* Wv    = (const float*)d_in[3];
  const float* Wp    = (const float*)d_in[4];
  const float* gamma = (const float*)d_in[5];
  const float* beta  = (const float*)d_in[6];
  const float* mean  = (const float*)d_in[7];
  const float* var   = (const float*)d_in[8];
  float* out = (float*)d_out;

  char* wsp = (char*)d_ws;
  unsigned short* qhp = (unsigned short*)wsp; wsp += (size_t)BD * ND * DA * 2;
  unsigned short* khp = (unsigned short*)wsp; wsp += (size_t)BD * ND * DA * 2;
  unsigned short* klp = (unsigned short*)wsp; wsp += (size_t)BD * ND * DA * 2;
  unsigned short* vT  = (unsigned short*)wsp; wsp += (size_t)BD * CD * ND * 2;
  unsigned short* xTh = (unsigned short*)wsp; wsp += (size_t)BD * ND * CD * 2;  // aliased as y
  unsigned short* xTl = (unsigned short*)wsp; wsp += (size_t)BD * ND * CD * 2;
  unsigned short* Wch = (unsigned short*)wsp; wsp += (size_t)384 * 256 * 2;
  unsigned short* Wcl = (unsigned short*)wsp; wsp += (size_t)384 * 256 * 2;
  unsigned short* Wph = (unsigned short*)wsp; wsp += (size_t)256 * 256 * 2;
  unsigned short* Wpl = (unsigned short*)wsp; wsp += (size_t)256 * 256 * 2;
  float* Drec = (float*)wsp; wsp += (size_t)BD * ND * 4;
  float* Dp   = (float*)wsp; wsp += (size_t)2 * BD * ND * 4;
  unsigned short* y = xTh;  // xTh consumed+overwritten by k_attn epilogue

  dim3 blk(256), blk5(512);
  k_prep<<<dim3(ND / 64, CD / 64, BD), blk, 0, stream>>>(x, xTh, xTl);
  k_prepW<<<dim3(160), blk, 0, stream>>>(Wq, Wk, Wv, Wp, Wch, Wcl, Wph, Wpl);
  k_proj<<<dim3(ND / 128, BD), blk5, 0, stream>>>(xTh, xTl, Wch, Wcl, qhp, khp,
                                                  klp, vT);
  k_colsum<<<dim3(512), blk5, 0, stream>>>(qhp, khp, klp, Dp);
  k_rcp<<<dim3(32), blk, 0, stream>>>(Dp, Drec);
  k_attn<<<dim3(256), blk5, 0, stream>>>(qhp, khp, klp, vT, Drec, y, xTl);
  k_final<<<dim3(2048), blk, 0, stream>>>(y, Wph, x, gamma, beta, mean, var, out);
}